// Round 8
// baseline (438.196 us; speedup 1.0000x reference)
//
#include <hip/hip_runtime.h>
#include <math.h>

#define BB 4
#define S 1024
#define D 512
#define H 8
#define DKH 64

#define ATT_LD 1032   // att row stride (shorts): 516 dwords == 4 mod 32 (2-way = free)
#define LOG2E 1.4426950408889634f

typedef __attribute__((ext_vector_type(8))) short bf16x8;
typedef __attribute__((ext_vector_type(4))) float f32x4;

#if __has_builtin(__builtin_amdgcn_exp2f)
#define EXP2(x) __builtin_amdgcn_exp2f(x)
#else
#define EXP2(x) exp2f(x)
#endif
#if __has_builtin(__builtin_amdgcn_sqrtf)
#define SQRTF(x) __builtin_amdgcn_sqrtf(x)
#else
#define SQRTF(x) sqrtf(x)
#endif
#if __has_builtin(__builtin_amdgcn_rcpf)
#define RCPF(x) __builtin_amdgcn_rcpf(x)
#else
#define RCPF(x) (1.0f / (x))
#endif

__device__ __forceinline__ unsigned short f2bf(float f){
  unsigned int u = __float_as_uint(f);
  u += 0x7FFFu + ((u >> 16) & 1u);
  return (unsigned short)(u >> 16);
}
__device__ __forceinline__ unsigned short f2bf_rhu(float f){
  return (unsigned short)((__float_as_uint(f) + 0x8000u) >> 16);
}
__device__ __forceinline__ unsigned int pk_rhu(float lo, float hi){
  unsigned int a = __float_as_uint(lo) + 0x8000u;
  unsigned int b = __float_as_uint(hi) + 0x8000u;
#if __has_builtin(__builtin_amdgcn_perm)
  return __builtin_amdgcn_perm(b, a, 0x07060302u);
#else
  return (a >> 16) | (b & 0xffff0000u);
#endif
}
__device__ __forceinline__ float bf2f(unsigned int v){
  return __uint_as_float(v << 16);
}
__device__ __forceinline__ f32x4 MFMA(bf16x8 a, bf16x8 b, f32x4 c){
  return __builtin_amdgcn_mfma_f32_16x16x32_bf16(a, b, c, 0, 0, 0);
}
__device__ __forceinline__ void gl_lds16(const void* g, void* l){
  __builtin_amdgcn_global_load_lds(
      (const __attribute__((address_space(1))) void*)g,
      (__attribute__((address_space(3))) void*)l, 16, 0, 0);
}

// ---- DPP cross-lane (pure VALU pipe) ----
template<int CTRL>
__device__ __forceinline__ float dppadd(float v){
  int s = __builtin_amdgcn_update_dpp(0, __float_as_int(v), CTRL, 0xf, 0xf, true);
  return v + __int_as_float(s);
}
__device__ __forceinline__ float rdl(float v, int l){
  return __int_as_float(__builtin_amdgcn_readlane(__float_as_int(v), l));
}
__device__ __forceinline__ void wave_scan64(float v, int lane, float& incl, float& total){
  float r = dppadd<0x111>(v);
  r = dppadd<0x112>(r);
  r = dppadd<0x114>(r);
  r = dppadd<0x118>(r);
  float t0 = rdl(r, 15), t1 = rdl(r, 31), t2 = rdl(r, 47), t3 = rdl(r, 63);
  const int row = lane >> 4;
  float off = (row > 0 ? t0 : 0.f) + (row > 1 ? t1 : 0.f) + (row > 2 ? t2 : 0.f);
  incl = r + off;
  total = (t0 + t1) + (t2 + t3);
}
__device__ __forceinline__ float wave_sum64(float v){
  float r = dppadd<0x111>(v);
  r = dppadd<0x112>(r);
  r = dppadd<0x114>(r);
  r = dppadd<0x118>(r);
  return (rdl(r, 15) + rdl(r, 31)) + (rdl(r, 47) + rdl(r, 63));
}

__device__ __forceinline__ float blk_sum(float* r, int t, float v){
  r[t] = v; __syncthreads();
  for (int s = 128; s > 0; s >>= 1){
    if (t < s) r[t] += r[t + s];
    __syncthreads();
  }
  float res = r[0]; __syncthreads();
  return res;
}

// ================= batched projection GEMM (M=4096,N=512,K=512) =================
struct GemmJobs {
  const unsigned short* A[4];
  const unsigned short* W[4];
  const float* bias[4];
  void* C[4];
};
template<int OUTBF>
__global__ __launch_bounds__(256) void mfma_gemm_b(GemmJobs jb)
{
  __shared__ __align__(16) short As[128][32];
  __shared__ __align__(16) short Ws[128][32];
  const int t = threadIdx.x;
  const int z = blockIdx.z;
  const int n0 = blockIdx.x * 128, m0 = blockIdx.y * 128;
  const unsigned short* A = jb.A[z];
  const unsigned short* W = jb.W[z];
  const float* bias = jb.bias[z];
  const int w = t >> 6, lane = t & 63;
  const int wm = (w >> 1) << 6, wn = (w & 1) << 6;
  const int lm = lane & 15, q = lane >> 4;
  const int r = t >> 2, cc = (t & 3) << 3;
  char* ldsA = ((char*)&As[0][0]) + w * 1024;
  char* ldsW = ((char*)&Ws[0][0]) + w * 1024;
  f32x4 acc[4][4];
  #pragma unroll
  for (int a_ = 0; a_ < 4; a_++)
    #pragma unroll
    for (int b_ = 0; b_ < 4; b_++)
      acc[a_][b_] = (f32x4){0.f, 0.f, 0.f, 0.f};
  for (int k0 = 0; k0 < D; k0 += 32){
    gl_lds16(&A[(size_t)(m0 + r)      * D + k0 + cc], ldsA);
    gl_lds16(&A[(size_t)(m0 + r + 64) * D + k0 + cc], ldsA + 4096);
    gl_lds16(&W[(size_t)(n0 + r)      * D + k0 + cc], ldsW);
    gl_lds16(&W[(size_t)(n0 + r + 64) * D + k0 + cc], ldsW + 4096);
    __syncthreads();
    bf16x8 af[4], bf[4];
    #pragma unroll
    for (int mt = 0; mt < 4; mt++) af[mt] = *(const bf16x8*)&As[wm + mt*16 + lm][q*8];
    #pragma unroll
    for (int nt = 0; nt < 4; nt++) bf[nt] = *(const bf16x8*)&Ws[wn + nt*16 + lm][q*8];
    #pragma unroll
    for (int mt = 0; mt < 4; mt++)
      #pragma unroll
      for (int nt = 0; nt < 4; nt++)
        acc[mt][nt] = MFMA(af[mt], bf[nt], acc[mt][nt]);
    __syncthreads();
  }
  #pragma unroll
  for (int nt = 0; nt < 4; nt++){
    const int n = n0 + wn + nt*16 + lm;
    const float bs = bias[n];
    #pragma unroll
    for (int mt = 0; mt < 4; mt++){
      const int mb = m0 + wm + mt*16 + (q << 2);
      f32x4 c = acc[mt][nt];
      #pragma unroll
      for (int rr = 0; rr < 4; rr++){
        float vv = c[rr] + bs;
        if (OUTBF)
          ((unsigned short*)jb.C[z])[(size_t)(mb + rr) * D + n] = f2bf(vv);
        else
          ((float*)jb.C[z])[(size_t)(mb + rr) * D + n] = vv;
      }
    }
  }
}

// ================= V transpose: VT[bh][64][S] from V[b][S][D] =================
#define KS_LD 66
struct VTArgs { const unsigned short* v[2]; unsigned short* vt[2]; };
__global__ __launch_bounds__(256) void vt_kernel(VTArgs a)
{
  __shared__ unsigned short tile[64 * KS_LD];
  const int z = blockIdx.z, bh = blockIdx.y, b = bh >> 3, h = bh & 7;
  const int j0 = blockIdx.x * 64;
  const int t = threadIdx.x;
  const unsigned short* vp = a.v[z];
  unsigned short* vtp = a.vt[z] + (size_t)bh * 64 * S;
  #pragma unroll
  for (int p = 0; p < 2; p++){
    int lin = t + p * 256, row = lin >> 3, c8 = (lin & 7) << 3;
    *(uint4*)&tile[row * KS_LD + c8] =
      *(const uint4*)&vp[((size_t)b * S + j0 + row) * D + h * DKH + c8];
  }
  __syncthreads();
  #pragma unroll
  for (int p = 0; p < 2; p++){
    int lin = t + p * 256, d = lin >> 3, c8 = (lin & 7) << 3;
    unsigned short tmp[8];
    #pragma unroll
    for (int jx = 0; jx < 8; jx++) tmp[jx] = tile[(c8 + jx) * KS_LD + d];
    *(uint4*)&vtp[(size_t)d * S + j0 + c8] = *(const uint4*)tmp;
  }
}

// ================= fused attention: scores -> decay -> AV =================
// 16-row i-blocks; 512 threads = 8 waves (2x concurrency vs 256).
// phase 1: 128 j/iter (8 iters); phase 2: 2 rows/wave; phase 3: split-K halves.
// grid (S/16, B*H, nz).
struct FAArgs {
  const unsigned short* qk[2];   // q==k source (bf16, [b][S][D])
  const unsigned short* vt[2];   // VT (bf16, [bh][64][S])
  unsigned short* ctx[2];        // out (bf16, [b][S][D])
  const float* g[2];
  const float* c3;               // fp32 [b][h][S] (C3 mode)
  int diag, zero_pad;
};
template<int C3>
__global__ __launch_bounds__(512, 6) void fused_attn(FAArgs a)
{
  __shared__ __align__(16) unsigned short att[16 * ATT_LD];   // 33,024 B
  __shared__ float pacc[16][65];                               //  4,160 B
  __shared__ float ls2s[16];
  const int t = threadIdx.x;
  const int z = blockIdx.z;
  const int bh = blockIdx.y, b = bh >> 3, h = bh & 7;
  const int i0 = blockIdx.x * 16;
  const int w = t >> 6, lane = t & 63, lm = lane & 15, q = lane >> 4;
  const unsigned short* qkp = a.qk[z];
  const unsigned short* vtp = a.vt[z] + (size_t)bh * 64 * S;
  unsigned short* ctxp = a.ctx[z];
  float gm2;
  { float gv = a.g[z][h];
    gm2 = -((gv > 20.f) ? gv : log1pf(expf(gv))) * LOG2E; }   // log2-space gamma

  // ---------- phase 1: scores tile [16 x 1024] -> att (bf16), 8 waves x 16 j ----------
  if (!C3){
    const size_t rowbase = (size_t)b * S;
    bf16x8 af0 = *(const bf16x8*)&qkp[(rowbase + i0 + lm) * D + h * DKH + q*8];
    bf16x8 af1 = *(const bf16x8*)&qkp[(rowbase + i0 + lm) * D + h * DKH + 32 + q*8];
    size_t kb = (rowbase + w*16 + lm) * D + h * DKH;
    bf16x8 bv0 = *(const bf16x8*)&qkp[kb + q*8];
    bf16x8 bv1 = *(const bf16x8*)&qkp[kb + 32 + q*8];
    for (int jc = 0; jc < S; jc += 128){
      bf16x8 nb0, nb1;
      if (jc + 128 < S){
        size_t kb2 = (rowbase + jc + 128 + w*16 + lm) * D + h * DKH;
        nb0 = *(const bf16x8*)&qkp[kb2 + q*8];
        nb1 = *(const bf16x8*)&qkp[kb2 + 32 + q*8];
      }
      f32x4 acc = (f32x4){0.f, 0.f, 0.f, 0.f};
      acc = MFMA(af0, bv0, acc);
      acc = MFMA(af1, bv1, acc);
      #pragma unroll
      for (int rr = 0; rr < 4; rr++)
        att[(q*4 + rr) * ATT_LD + jc + w*16 + lm] = f2bf_rhu(acc[rr] * 0.125f);
      bv0 = nb0; bv1 = nb1;
    }
  }
  __syncthreads();

  // ---------- phase 2: decay + double softmax, 2 rows/wave ----------
  const int jA0 = lane * 8, jB0 = 512 + lane * 8;

  float cH[16], erH[16];
  if (C3){
    const float* c3p = a.c3 + ((size_t)b * H + h) * S;
    #pragma unroll
    for (int sg = 0; sg < 2; sg++)
      #pragma unroll
      for (int p4 = 0; p4 < 2; p4++){
        float4 x = *(const float4*)&c3p[sg*512 + lane*8 + p4*4];
        cH[sg*8+p4*4+0] = x.x * LOG2E; cH[sg*8+p4*4+1] = x.y * LOG2E;
        cH[sg*8+p4*4+2] = x.z * LOG2E; cH[sg*8+p4*4+3] = x.w * LOG2E;
      }
    #pragma unroll
    for (int k = 0; k < 16; k++) erH[k] = EXP2(cH[k]);
  }

  auto decay_row = [&](const float (&c)[16], const float (&er)[16],
                       const int i, unsigned short* rowp, const int rl){
    const int jmax = i + a.diag;
    const bool skipB = (jmax < 512);     // wave-uniform (i0 multiple of 16)
    float pl[16];
    float runA = 0.f;
    #pragma unroll
    for (int k = 0; k < 8; k++){
      float e = (jA0 + k <= jmax) ? er[k] : 0.f;
      runA += e; pl[k] = runA;
    }
    float sA, TA;
    wave_scan64(runA, lane, sA, TA);
    float T = TA, sB = 0.f, runB = 0.f;
    if (!skipB){
      #pragma unroll
      for (int k = 0; k < 8; k++){
        float e = (jB0 + k <= jmax) ? er[8+k] : 0.f;
        runB += e; pl[8+k] = runB;
      }
      float TB;
      wave_scan64(runB, lane, sB, TB);
      T = TA + TB;
    }
    const float inv1 = RCPF(T);
    const float cbaseA = (T - (sA - runA)) * inv1;
    const float fiA = (float)(i - jA0);
    float ls2 = 0.f;
    #pragma unroll
    for (int k = 0; k < 8; k++){
      float remn = fmaf(-pl[k], inv1, cbaseA);
      float pos  = fabsf(fiA - (float)k);
      float dist = SQRTF(fmaxf(remn * pos, 0.f));
      float eff  = fmaxf(EXP2(gm2 * dist), 1e-5f);
      float pp   = EXP2(c[k] * eff);
      ls2 += pp; pl[k] = pp;
    }
    if (!skipB){
      const float cbaseB = (T - (TA + sB - runB)) * inv1;
      const float fiB = (float)(i - jB0);
      #pragma unroll
      for (int k = 0; k < 8; k++){
        float remn = fmaf(-pl[8+k], inv1, cbaseB);
        float pos  = fabsf(fiB - (float)k);
        float dist = SQRTF(fmaxf(remn * pos, 0.f));
        float eff  = fmaxf(EXP2(gm2 * dist), 1e-5f);
        float pp   = EXP2(c[8+k] * eff);
        ls2 += pp; pl[8+k] = pp;
      }
    } else {
      #pragma unroll
      for (int k = 0; k < 8; k++){ pl[8+k] = er[8+k]; ls2 += er[8+k]; }
    }
    ls2 = wave_sum64(ls2);
    if (lane == 0) ls2s[rl] = RCPF(ls2);
    #pragma unroll
    for (int sg = 0; sg < 2; sg++){
      uint4 o;
      o.x = pk_rhu(pl[sg*8+0], pl[sg*8+1]);
      o.y = pk_rhu(pl[sg*8+2], pl[sg*8+3]);
      o.z = pk_rhu(pl[sg*8+4], pl[sg*8+5]);
      o.w = pk_rhu(pl[sg*8+6], pl[sg*8+7]);
      *(uint4*)&rowp[sg*512 + lane*8] = o;
    }
  };

  #pragma unroll
  for (int rloc = 0; rloc < 2; rloc++){
    const int rl = w*2 + rloc;
    const int i = i0 + rl;
    unsigned short* rowp = &att[rl * ATT_LD];
    if (C3 && a.zero_pad && i == 0){
      uint4 zz = make_uint4(0u,0u,0u,0u);
      *(uint4*)&rowp[jA0] = zz;
      *(uint4*)&rowp[jB0] = zz;
      if (lane == 0) ls2s[0] = 1.f;
      continue;
    }
    if (C3){
      decay_row(cH, erH, i, rowp, rl);
    } else {
      float c[16], er[16];
      #pragma unroll
      for (int sg = 0; sg < 2; sg++){
        uint4 u = *(const uint4*)&rowp[sg*512 + lane*8];
        unsigned int uu[4] = {u.x, u.y, u.z, u.w};
        #pragma unroll
        for (int mel = 0; mel < 4; mel++){
          c[sg*8 + mel*2]     = bf2f(uu[mel] & 0xffffu) * LOG2E;
          c[sg*8 + mel*2 + 1] = bf2f(uu[mel] >> 16) * LOG2E;
        }
      }
      #pragma unroll
      for (int k = 0; k < 16; k++) er[k] = EXP2(c[k]);
      decay_row(c, er, i, rowp, rl);
    }
  }
  __syncthreads();

  // ---------- phase 3: ctx = att @ V, split-K over S halves ----------
  const int dg = ((w & 3) << 4) + lm;   // d column 0..63
  const int kh = (w >> 2) << 9;         // 0 or 512
  const unsigned short* vrow = &vtp[(size_t)dg * S + kh];
  bf16x8 bv0 = *(const bf16x8*)&vrow[q*8];
  bf16x8 bv1 = *(const bf16x8*)&vrow[32 + q*8];
  f32x4 acc = (f32x4){0.f,0.f,0.f,0.f};
  for (int kc = 0; kc < 512; kc += 64){
    bf16x8 nb0, nb1;
    if (kc + 64 < 512){
      nb0 = *(const bf16x8*)&vrow[kc + 64 + q*8];
      nb1 = *(const bf16x8*)&vrow[kc + 96 + q*8];
    }
    bf16x8 a0 = *(const bf16x8*)&att[lm * ATT_LD + kh + kc + q*8];
    bf16x8 a1 = *(const bf16x8*)&att[lm * ATT_LD + kh + kc + 32 + q*8];
    acc = MFMA(a0, bv0, acc);
    acc = MFMA(a1, bv1, acc);
    bv0 = nb0; bv1 = nb1;
  }
  if (w >= 4){
    #pragma unroll
    for (int rr = 0; rr < 4; rr++)
      pacc[q*4 + rr][dg] = acc[rr];
  }
  __syncthreads();
  if (w < 4){
    #pragma unroll
    for (int rr = 0; rr < 4; rr++){
      const int rl = q*4 + rr;
      const float tot = acc[rr] + pacc[rl][dg];
      const int row = i0 + rl;
      ctxp[((size_t)b * S + row) * D + h * DKH + dg] = f2bf(tot * ls2s[rl]);
    }
  }
}

// ================= residual + LayerNorm -> bf16 (batched) =================
struct LNJobs {
  const float* resid[2];
  const float* y[2];
  const float* ls[2];
  const float* lb[2];
  unsigned short* out[2];
  int bcast[2];
};
__global__ __launch_bounds__(256) void ln_residual_b(LNJobs j)
{
  const int z = blockIdx.y;
  const int r = blockIdx.x, t = threadIdx.x;
  __shared__ float red[256];
  const size_t base = (size_t)r * D;
  const float* resid = j.resid[z];
  const float* y = j.y[z];
  const int bcast = j.bcast[z];
  float r0 = bcast ? resid[t]       : resid[base + t];
  float r1 = bcast ? resid[t + 256] : resid[base + t + 256];
  float x0 = r0 + y[base + t];
  float x1 = r1 + y[base + t + 256];
  float mean = blk_sum(red, t, x0 + x1) * (1.0f / 512.0f);
  float d0 = x0 - mean, d1 = x1 - mean;
  float var = blk_sum(red, t, d0*d0 + d1*d1) * (1.0f / 512.0f);
  float inv = rsqrtf(var + 1e-5f);
  j.out[z][base + t]       = f2bf(d0 * inv * j.ls[z][t]       + j.lb[z][t]);
  j.out[z][base + t + 256] = f2bf(d1 * inv * j.ls[z][t + 256] + j.lb[z][t + 256]);
}

// ================= fp32 -> bf16 conversions =================
struct CvtJobs {
  const float* s[12];
  unsigned short* d[12];
  int n[12];
};
__global__ __launch_bounds__(256) void cvt_all(CvtJobs jb){
  const int z = blockIdx.y;
  const int n = jb.n[z];
  const float* s = jb.s[z];
  unsigned short* d = jb.d[z];
  for (int idx = blockIdx.x * 256 + threadIdx.x; idx < n; idx += gridDim.x * 256)
    d[idx] = f2bf(s[idx]);
}

// ================= know-derived small kernels (merged) =================
__global__ __launch_bounds__(256) void know_kernel(
    const float* __restrict__ know, const float* __restrict__ Wq3,
    const float* __restrict__ bq3, float* __restrict__ q3,
    const float* __restrict__ Wlk, const float* __restrict__ blk_,
    float* __restrict__ keyt)
{
  if (blockIdx.x < 128){
    const int wv = (blockIdx.x * 256 + threadIdx.x) >> 6;
    const int lane = threadIdx.x & 63;
    const float* wr = Wq3 + (size_t)wv * 512 + lane * 8;
    const float* kr = know + lane * 8;
    float4 w0 = *(const float4*)&wr[0], w1 = *(const float4*)&wr[4];
    float4 k0 = *(const float4*)&kr[0], k1 = *(const float4*)&kr[4];
    float p = w0.x*k0.x + w0.y*k0.y + w0.z*k0.z + w0.w*k0.w
            + w1.x*k1.x + w1.y*k1.y + w1.z*k1.z + w1.w*k1.w;
    p = wave_sum64(p);
    if (lane == 0) q3[wv] = p + bq3[wv];
  } else {
    int idx = (blockIdx.x - 128) * 256 + threadIdx.x;
    int h = idx >> 9, n = idx & 511;
    float acc = 0.f;
    for (int i = 0; i < 64; i++) acc += know[h * 64 + i] * Wlk[(size_t)n * 64 + i];
    keyt[idx] = 1.f / (1.f + __expf(-(acc + blk_[n])));
  }
}

__global__ __launch_bounds__(256) void scores3_kernel(
    const float* __restrict__ q3, const unsigned short* __restrict__ k3,
    float* __restrict__ c3)
{
  int idx = blockIdx.x * 256 + threadIdx.x;   // (b*H+h)*S + j
  int j  = idx & (S - 1);
  int bh = idx >> 10;
  int h  = bh & 7, b = bh >> 3;
  const unsigned short* kp = k3 + ((size_t)b * S + j) * D + h * DKH;
  const float* qp = q3 + h * DKH;
  float acc = 0.f;
  #pragma unroll
  for (int d8 = 0; d8 < 64; d8 += 8){
    uint4 u = *(const uint4*)&kp[d8];
    unsigned int uu[4] = {u.x, u.y, u.z, u.w};
    #pragma unroll
    for (int mel = 0; mel < 4; mel++){
      acc += qp[d8 + 2*mel]     * bf2f(uu[mel] & 0xffffu);
      acc += qp[d8 + 2*mel + 1] * bf2f(uu[mel] >> 16);
    }
  }
  c3[idx] = acc * 0.125f;
}

__global__ __launch_bounds__(256) void alphas_kernel(
    const float* __restrict__ keyt, const float* __restrict__ q_emb,
    float* __restrict__ alpha)
{
  const int row = blockIdx.x * 4 + (threadIdx.x >> 6);
  const int l = threadIdx.x & 63;
  const int h = l >> 3, sub = l & 7;
  const float* qr = q_emb + (size_t)row * D;
  const float* kt = keyt + h * D;
  float p = 0.f;
  for (int d = sub; d < D; d += 8) p += kt[d] * qr[d];
  p += __shfl_xor(p, 1, 64);
  p += __shfl_xor(p, 2, 64);
  p += __shfl_xor(p, 4, 64);
  float m = p;
  m = fmaxf(m, __shfl_xor(m, 8, 64));
  m = fmaxf(m, __shfl_xor(m, 16, 64));
  m = fmaxf(m, __shfl_xor(m, 32, 64));
  float e = __expf(p - m);
  float ssum = e;
  ssum += __shfl_xor(ssum, 8, 64);
  ssum += __shfl_xor(ssum, 16, 64);
  ssum += __shfl_xor(ssum, 32, 64);
  if (sub == 0) alpha[(size_t)row * H + h] = e / ssum;
}

// ================= fused val GEMM + sigmoid + alpha-combine =================
__global__ __launch_bounds__(256) void val_fused(
    const unsigned short* __restrict__ Ah,
    const unsigned short* __restrict__ Wv,
    const float* __restrict__ blv,
    const float* __restrict__ alpha,
    float* __restrict__ out)
{
  __shared__ __align__(16) short As[128][32];
  __shared__ __align__(16) short Ws[128][32];
  __shared__ float als[128];
  const int t = threadIdx.x;
  const int n0 = blockIdx.x * 128, m0 = blockIdx.y * 128;
  if (t < 128) als[t] = alpha[m0 + t];
  const int w = t >> 6, lane = t & 63;
  const int wm = (w >> 1) << 6, wn = (w & 1) << 6;
  const int lm = lane & 15, q = lane >> 4;
  const int r = t >> 2, cc = (t & 3) << 3;
  f32x4 acc[4][4];
  #pragma unroll
  for (int a_ = 0; a_ < 4; a_++)
    #pragma unroll
    for (int b_ = 0; b_ < 4; b_++)
      acc[a_][b_] = (f32x4){0.f, 0.f, 0.f, 0.f};
  for (int k0 = 0; k0 < 64; k0 += 32){
    *(uint4*)&As[r][cc]      = *(const uint4*)&Ah[(size_t)(m0 + r) * 64 + k0 + cc];
    *(uint4*)&As[r + 64][cc] = *(const uint4*)&Ah[(size_t)(m0 + r + 64) * 64 + k0 + cc];
    *(uint4*)&Ws[r][cc]      = *(const uint4*)&Wv[(size_t)(n0 + r) * 64 + k0 + cc];
    *(uint4*)&Ws[r + 64][cc] = *(const uint4*)&Wv[(size_t)(n0 + r + 64) * 64 + k0 + cc];
    __syncthreads();
    bf16x8 af[4], bf[4];
    #pragma unroll
    for (int mt = 0; mt < 4; mt++) af[mt] = *(const bf16x8*)&As[wm + mt*16 + lm][q*8];
    #pragma unroll
    for (int nt = 0; nt < 4; nt++) bf[nt] = *(const bf16x8*)&Ws[wn + nt*16 + lm][q*8];
    #pragma unroll
    for (int mt = 0; mt < 4; mt++)
      #pragma unroll
      for (int nt = 0; nt < 4; nt++)
        acc[mt][nt] = MFMA(af[mt], bf[nt], acc[mt][nt]);
    __syncthreads();
  }
  #pragma unroll
  for (int nt = 0; nt < 4; nt++){
    const int n = n0 + wn + nt*16 + lm;
    const float bs = blv[n];
    #pragma unroll
    for (int mt = 0; mt < 4; mt++){
      const int mb = m0 + wm + mt*16;
      f32x4 c = acc[mt][nt];
      float part = 0.f;
      #pragma unroll
      for (int rr = 0; rr < 4; rr++){
        const int ml = (mb - m0) + (q << 2) + rr;
        float sg = 1.f / (1.f + __expf(-(c[rr] + bs)));
        part += als[ml] * sg;
      }
      part += __shfl_xor(part, 16, 64);
      if ((q & 1) == 0){
        const int srow = (mb >> 3) + (q >> 1);
        out[(size_t)srow * D + n] = part;
      }
    }
  }
}

// ================= orchestration =================
extern "C" void kernel_launch(void* const* d_in, const int* in_sizes, int n_in,
                              void* d_out, int out_size, void* d_ws, size_t ws_size,
                              hipStream_t stream) {
  const float* q_emb  = (const float*)d_in[0];
  const float* qa_emb = (const float*)d_in[1];
  const float* Wq1 = (const float*)d_in[2],  *bq1 = (const float*)d_in[3];
  const float* Wv1 = (const float*)d_in[4],  *bv1 = (const float*)d_in[5];
  const float* Wo1 = (const float*)d_in[6],  *bo1 = (const float*)d_in[7];
  const float* g1  = (const float*)d_in[8],  *ls1 = (const float*)d_in[9],  *lb1 = (const float*)d_in[10];
  const float* Wq2 = (const float*)d_in[11], *bq2 = (const float*)d_in[12];
  const float* Wv2 = (const float*)d_in[13], *bv2 = (const float*)d_in[14];
  const float* Wo2 = (const float*)d_in[15], *bo2 = (const float*)d_in[16];
  const float* g2  = (const float*)d_in[17], *ls2 = (const float*)d_in[18], *lb2 = (const float*)d_in[19];
  const float* Wq3 = (const float*)d_in[20], *bq3 = (const float*)d_in[21];
  const float* Wk3 = (const float*)d_in[22], *bk3 = (const float*)d_in[23];
  const float* Wv3 = (const float*)d_in[24], *bv3 = (const float*)d_in[25];
  const float* Wo3 = (const float*)d_in[26], *bo3 = (const float*)d_in[27];
  const float* g3  = (const float*)d_in[28], *ls3 = (const float*)d_in[29], *lb3 = (const float*)d_in[30];
  const float* know = (const float*)d_in[31];
  const float* Wlk  = (const float*)d_in[32], *b_lk = (const float*)d_in[33];
  const float* Wlv  = (const float*)d_in[34], *b_lv = (const float*)d_in[35];
  float* outp = (float*)d_out;

  const size_t NSD = (size_t)BB * S * D;   // 2,097,152
  unsigned short* p = (unsigned short*)d_ws;
  unsigned short* qk1b = p; p += NSD;
  unsigned short* v1b  = p; p += NSD;
  unsigned short* qk2b = p; p += NSD;
  unsigned short* v2b  = p; p += NSD;
  unsigned short* k3b  = p; p += NSD;
  unsigned short* v3b  = p; p += NSD;
  unsigned short* ctx1b= p; p += NSD;
  unsigned short* ctx2b= p; p += NSD;
  unsigned short* ctx3b= p; p += NSD;
  unsigned short* xqb  = p; p += NSD;
  unsigned short* xab  = p; p += NSD;
  unsigned short* hqb  = p; p += NSD;
  unsigned short* hab  = p; p += NSD;
  unsigned short* hfb  = p; p += NSD;
  unsigned short* vt1  = p; p += NSD;   // [32][64][1024]
  unsigned short* vt2  = p; p += NSD;
  unsigned short* vt3  = p; p += NSD;
  unsigned short* wb   = p; p += (size_t)9 * D * D;
  unsigned short* wlvb = p; p += (size_t)D * DKH;
  float* yv0   = (float*)p;
  float* yv1   = yv0 + NSD;
  float* q3    = yv1 + NSD;
  float* keyt  = q3 + 512;
  float* c3    = keyt + 4096;
  float* alpha = c3 + (size_t)BB * H * S;

  unsigned short* Wq1b = wb + 0*(size_t)D*D;
  unsigned short* Wv1b = wb + 1*(size_t)D*D;
  unsigned short* Wo1b = wb + 2*(size_t)D*D;
  unsigned short* Wq2b = wb + 3*(size_t)D*D;
  unsigned short* Wv2b = wb + 4*(size_t)D*D;
  unsigned short* Wo2b = wb + 5*(size_t)D*D;
  unsigned short* Wk3b = wb + 6*(size_t)D*D;
  unsigned short* Wv3b = wb + 7*(size_t)D*D;
  unsigned short* Wo3b = wb + 8*(size_t)D*D;

  // ---- conversions ----
  CvtJobs jb;
  jb.s[0] = q_emb;  jb.d[0] = xqb;  jb.n[0] = (int)NSD;
  jb.s[1] = qa_emb; jb.d[1] = xab;  jb.n[1] = (int)NSD;
  jb.s[2] = Wq1; jb.d[2] = Wq1b; jb.n[2] = D*D;
  jb.s[3] = Wv1; jb.d[3] = Wv1b; jb.n[3] = D*D;
  jb.s[4] = Wo1; jb.d[4] = Wo1b; jb.n[4] = D*D;
  jb.s[5] = Wq2; jb.d[5] = Wq2b; jb.n[5] = D*D;
  jb.s[6] = Wv2; jb.d[6] = Wv2b; jb.n[6] = D*D;
  jb.s[7] = Wo2; jb.d[7] = Wo2b; jb.n[7] = D*D;
  jb.s[8] = Wk3; jb.d[8] = Wk3b; jb.n[8] = D*D;
  jb.s[9] = Wv3; jb.d[9] = Wv3b; jb.n[9] = D*D;
  jb.s[10] = Wo3; jb.d[10] = Wo3b; jb.n[10] = D*D;
  jb.s[11] = Wlv; jb.d[11] = wlvb; jb.n[11] = D*DKH;
  cvt_all<<<dim3(256, 12), 256, 0, stream>>>(jb);

  // ---- blocks 1&2: projections (z=4) ----
  {
    GemmJobs g;
    g.A[0]=xqb; g.W[0]=Wq1b; g.bias[0]=bq1; g.C[0]=qk1b;
    g.A[1]=xqb; g.W[1]=Wv1b; g.bias[1]=bv1; g.C[1]=v1b;
    g.A[2]=xab; g.W[2]=Wq2b; g.bias[2]=bq2; g.C[2]=qk2b;
    g.A[3]=xab; g.W[3]=Wv2b; g.bias[3]=bv2; g.C[3]=v2b;
    mfma_gemm_b<1><<<dim3(4, 32, 4), 256, 0, stream>>>(g);
  }
  { VTArgs a; a.v[0]=v1b; a.v[1]=v2b; a.vt[0]=vt1; a.vt[1]=vt2;
    vt_kernel<<<dim3(16, 32, 2), 256, 0, stream>>>(a); }
  { FAArgs a;
    a.qk[0]=qk1b; a.qk[1]=qk2b; a.vt[0]=vt1; a.vt[1]=vt2;
    a.ctx[0]=ctx1b; a.ctx[1]=ctx2b; a.g[0]=g1; a.g[1]=g2;
    a.c3=nullptr; a.diag=0; a.zero_pad=0;
    fused_attn<0><<<dim3(64, 32, 2), 512, 0, stream>>>(a); }
  {
    GemmJobs g;
    g.A[0]=ctx1b; g.W[0]=Wo1b; g.bias[0]=bo1; g.C[0]=yv0;
    g.A[1]=ctx2b; g.W[1]=Wo2b; g.bias[1]=bo2; g.C[1]=yv1;
    g.A[2]=ctx1b; g.W[2]=Wo1b; g.bias[2]=bo1; g.C[2]=yv0;
    g.A[3]=ctx1b; g.W[3]=Wo1b; g.bias[3]=bo1; g.C[3]=yv0;
    mfma_gemm_b<0><<<dim3(4, 32, 2), 256, 0, stream>>>(g);
  }
  {
    LNJobs lj;
    lj.resid[0]=q_emb;  lj.y[0]=yv0; lj.ls[0]=ls1; lj.lb[0]=lb1; lj.out[0]=hqb; lj.bcast[0]=0;
    lj.resid[1]=qa_emb; lj.y[1]=yv1; lj.ls[1]=ls2; lj.lb[1]=lb2; lj.out[1]=hab; lj.bcast[1]=0;
    ln_residual_b<<<dim3(BB*S, 2), 256, 0, stream>>>(lj);
  }

  // ---- block 3 ----
  know_kernel<<<144, 256, 0, stream>>>(know, Wq3, bq3, q3, Wlk, b_lk, keyt);
  {
    GemmJobs g;
    g.A[0]=hqb; g.W[0]=Wk3b; g.bias[0]=bk3; g.C[0]=k3b;
    g.A[1]=hab; g.W[1]=Wv3b; g.bias[1]=bv3; g.C[1]=v3b;
    g.A[2]=hqb; g.W[2]=Wk3b; g.bias[2]=bk3; g.C[2]=k3b;
    g.A[3]=hqb; g.W[3]=Wk3b; g.bias[3]=bk3; g.C[3]=k3b;
    mfma_gemm_b<1><<<dim3(4, 32, 2), 256, 0, stream>>>(g);
  }
  { VTArgs a; a.v[0]=v3b; a.v[1]=v3b; a.vt[0]=vt3; a.vt[1]=vt3;
    vt_kernel<<<dim3(16, 32, 1), 256, 0, stream>>>(a); }
  scores3_kernel<<<128, 256, 0, stream>>>(q3, k3b, c3);
  { FAArgs a;
    a.qk[0]=k3b; a.qk[1]=k3b; a.vt[0]=vt3; a.vt[1]=vt3;
    a.ctx[0]=ctx3b; a.ctx[1]=ctx3b; a.g[0]=g3; a.g[1]=g3;
    a.c3=c3; a.diag=-1; a.zero_pad=1;
    fused_attn<1><<<dim3(64, 32, 1), 512, 0, stream>>>(a); }
  {
    GemmJobs g;
    g.A[0]=ctx3b; g.W[0]=Wo3b; g.bias[0]=bo3; g.C[0]=yv0;
    g.A[1]=ctx3b; g.W[1]=Wo3b; g.bias[1]=bo3; g.C[1]=yv0;
    g.A[2]=ctx3b; g.W[2]=Wo3b; g.bias[2]=bo3; g.C[2]=yv0;
    g.A[3]=ctx3b; g.W[3]=Wo3b; g.bias[3]=bo3; g.C[3]=yv0;
    mfma_gemm_b<0><<<dim3(4, 32, 1), 256, 0, stream>>>(g);
  }
  {
    LNJobs lj;
    lj.resid[0]=know; lj.y[0]=yv0; lj.ls[0]=ls3; lj.lb[0]=lb3; lj.out[0]=hfb; lj.bcast[0]=1;
    lj.resid[1]=know; lj.y[1]=yv0; lj.ls[1]=ls3; lj.lb[1]=lb3; lj.out[1]=hfb; lj.bcast[1]=1;
    ln_residual_b<<<dim3(BB*S, 1), 256, 0, stream>>>(lj);
  }

  // ---- final combine ----
  alphas_kernel<<<1024, 256, 0, stream>>>(keyt, q_emb, alpha);
  val_fused<<<dim3(4, 256), 256, 0, stream>>>(hfb, wlvb, b_lv, alpha, outp);
}